// Round 16
// baseline (286.556 us; speedup 1.0000x reference)
//
#include <hip/hip_runtime.h>

// Problem constants (fixed by setup_inputs)
constexpr int H_  = 32;
constexpr int N_  = 256;
constexpr int BS_ = 32;
constexpr int W_  = 128;
constexpr int T_  = 4096;
constexpr int D_  = 128;
constexpr int NQ_ = 8192;          // N_*BS_
constexpr float SCALE_  = 0.08838834764831845f;  // 1/sqrt(128)
constexpr float L2E_    = 1.4426950408889634f;
constexpr float MFLOOR_ = -1.0e28f;
constexpr float DEFER_  = 8.0f;                  // defer-max threshold (T13)

typedef __attribute__((ext_vector_type(4))) float f4;
typedef __attribute__((ext_vector_type(4))) short s4;
typedef __attribute__((ext_vector_type(8))) short s8;
typedef __attribute__((ext_vector_type(4))) float fx4;
typedef __attribute__((ext_vector_type(2))) int i2;

// one v_cvt_pk_bf16_f32: D.lo = bf16(a), D.hi = bf16(b)  (RNE)
__device__ __forceinline__ int pack2(float a, float b) {
  int r;
  asm("v_cvt_pk_bf16_f32 %0, %1, %2" : "=v"(r) : "v"(a), "v"(b));
  return r;
}

union frag_u { int w[4]; s8 v; };

__global__ __launch_bounds__(64, 2)
void mtp_attn_kernel(const float* __restrict__ q,
                     const float* __restrict__ k_ctx,
                     const float* __restrict__ v_ctx,
                     const float* __restrict__ k_draft,
                     const float* __restrict__ v_draft,
                     const int* __restrict__ anchor,
                     const int* __restrict__ keepm,
                     float* __restrict__ out)
{
  // 8192 one-wave blocks; XCD-chunked swizzle (8192 % 8 == 0 -> bijective)
  int b = blockIdx.x;
  int u = (b & 7) * 1024 + (b >> 3);
  const int h = u >> 8;
  const int n = u & 255;

  const int lane = threadIdx.x;  // 0..63 — ONE wave per unit, zero barriers
  const int l15  = lane & 15;
  const int g    = lane >> 4;    // 0..3
  const int c4v  = lane & 31;    // V staging f4 column
  const int rb2  = lane >> 5;    // 0..1

  const int A  = anchor[n];
  const int kp = keepm[n];
  const int wm = W_ - A;         // ctx key valid iff key >= wm

  // Wave-private V^T: bf16 [128 d][36] = 9216 B. Same-wave DS ordering only.
  __shared__ __align__(16) short vT[128 * 36];

  // ---- Q B-fragments for BOTH q-tiles (t=0: q0..15, t=1: q16..31) ----
  s8 qb[2][4];
#pragma unroll
  for (int t = 0; t < 2; ++t) {
    const float* qrow = q + ((size_t)h * NQ_ + (size_t)n * BS_ + t * 16 + l15) * D_;
#pragma unroll
    for (int ks = 0; ks < 4; ++ks) {
      f4 f0 = *reinterpret_cast<const f4*>(qrow + ks * 32 + g * 4);
      f4 f1 = *reinterpret_cast<const f4*>(qrow + ks * 32 + 16 + g * 4);
      frag_u uq;
      uq.w[0] = pack2(f0[0], f0[1]); uq.w[1] = pack2(f0[2], f0[3]);
      uq.w[2] = pack2(f1[0], f1[1]); uq.w[3] = pack2(f1[2], f1[3]);
      qb[t][ks] = uq.v;
    }
  }

  const float* kcb = k_ctx + (size_t)h * T_ * D_;
  const float* vcb = v_ctx + (size_t)h * T_ * D_;
  const float* kdb = k_draft + ((size_t)h * NQ_ + (size_t)n * BS_) * D_;
  const float* vdb = v_draft + ((size_t)h * NQ_ + (size_t)n * BS_) * D_;

  f4 kf[16];   // K A-fragments, direct from global (r7-verified mapping)
  f4 vr[16];   // V chunk staging regs

  auto loadK = [&](int c) {      // lane covers K rows l15 and 16+l15 of the chunk
    const float* s0; const float* s1;
    if (c < 4) {
      int i0 = A - W_ + c * 32 + l15;  int i1 = i0 + 16;
      i0 = i0 < 0 ? 0 : i0;            i1 = i1 < 0 ? 0 : i1;
      s0 = kcb + (size_t)i0 * D_;      s1 = kcb + (size_t)i1 * D_;
    } else {
      s0 = kdb + (size_t)l15 * D_;     s1 = s0 + 16 * D_;
    }
#pragma unroll
    for (int ks = 0; ks < 4; ++ks) {
      kf[ks * 2 + 0]     = *reinterpret_cast<const f4*>(s0 + ks * 32 + g * 4);
      kf[ks * 2 + 1]     = *reinterpret_cast<const f4*>(s0 + ks * 32 + 16 + g * 4);
      kf[8 + ks * 2 + 0] = *reinterpret_cast<const f4*>(s1 + ks * 32 + g * 4);
      kf[8 + ks * 2 + 1] = *reinterpret_cast<const f4*>(s1 + ks * 32 + 16 + g * 4);
    }
  };
  auto loadV = [&](int c) {      // rows p*16 + rb2*8 + i, f4-col c4v
#pragma unroll
    for (int p = 0; p < 2; ++p)
#pragma unroll
      for (int i = 0; i < 8; ++i) {
        int row = p * 16 + rb2 * 8 + i;
        const float* src;
        if (c < 4) { int idx = A - W_ + c * 32 + row; idx = idx < 0 ? 0 : idx; src = vcb + (size_t)idx * D_; }
        else       { src = vdb + (size_t)row * D_; }
        vr[p * 8 + i] = reinterpret_cast<const f4*>(src)[c4v];
      }
  };
  auto writeV = [&]() {          // transpose -> vT[d][key]; keys k0..k0+7 per (p)
#pragma unroll
    for (int p = 0; p < 2; ++p) {
      int k0 = p * 16 + rb2 * 8;
#pragma unroll
      for (int j = 0; j < 4; ++j) {
        int d = c4v * 4 + j;
        i2 w1 = { pack2(vr[p * 8 + 0][j], vr[p * 8 + 1][j]),
                  pack2(vr[p * 8 + 2][j], vr[p * 8 + 3][j]) };
        i2 w2 = { pack2(vr[p * 8 + 4][j], vr[p * 8 + 5][j]),
                  pack2(vr[p * 8 + 6][j], vr[p * 8 + 7][j]) };
        *reinterpret_cast<i2*>(vT + d * 36 + k0)     = w1;
        *reinterpret_cast<i2*>(vT + d * 36 + k0 + 4) = w2;
      }
    }
  };

  loadK(0); loadV(0);

  float m[2]  = { -3.0e38f, -3.0e38f };
  float ls[2] = { 0.0f, 0.0f };
  fx4 oacc[2][8];
#pragma unroll
  for (int t = 0; t < 2; ++t)
#pragma unroll
    for (int nt = 0; nt < 8; ++nt) oacc[t][nt] = {0.f, 0.f, 0.f, 0.f};

#pragma unroll
  for (int c = 0; c < 5; ++c) {
    // ---- V(c) -> private LDS; refill vr for c+1 (lands during compute) ----
    writeV();
    if (c < 4) loadV(c + 1);

    // ---- QK^T swapped: st[t2][t] = mfma(K, Q_t); K conversion shared ----
    fx4 st[2][2];
#pragma unroll
    for (int t2 = 0; t2 < 2; ++t2)
#pragma unroll
      for (int t = 0; t < 2; ++t) st[t2][t] = {0.f, 0.f, 0.f, 0.f};
    __builtin_amdgcn_s_setprio(1);
#pragma unroll
    for (int ks = 0; ks < 4; ++ks)
#pragma unroll
      for (int t2 = 0; t2 < 2; ++t2) {
        f4 f0 = kf[t2 * 8 + ks * 2 + 0];
        f4 f1 = kf[t2 * 8 + ks * 2 + 1];
        frag_u uk;
        uk.w[0] = pack2(f0[0], f0[1]); uk.w[1] = pack2(f0[2], f0[3]);
        uk.w[2] = pack2(f1[0], f1[1]); uk.w[3] = pack2(f1[2], f1[3]);
        st[t2][0] = __builtin_amdgcn_mfma_f32_16x16x32_bf16(uk.v, qb[0][ks], st[t2][0], 0, 0, 0);
        st[t2][1] = __builtin_amdgcn_mfma_f32_16x16x32_bf16(uk.v, qb[1][ks], st[t2][1], 0, 0, 0);
      }
    __builtin_amdgcn_s_setprio(0);
    if (c < 4) loadK(c + 1);     // kf consumed; refill with full-chunk flight window

    // ---- mask + scale + lane-local max per q-tile (in place) ----
    float cmx[2] = { -3.0e38f, -3.0e38f };
#pragma unroll
    for (int t2 = 0; t2 < 2; ++t2) {
      int kb0 = c * 32 + t2 * 16 + g * 4;
#pragma unroll
      for (int r = 0; r < 4; ++r) {
        bool valid = (c == 4) || (kb0 + r >= wm);
#pragma unroll
        for (int t = 0; t < 2; ++t) {
          float v = st[t2][t][r] * SCALE_;
          v = valid ? v : -1.0e30f;
          st[t2][t][r] = v;
          cmx[t] = fmaxf(cmx[t], v);
        }
      }
    }
    if (c == 0) {
#pragma unroll
      for (int t = 0; t < 2; ++t) {
        float cm = fmaxf(cmx[t], __shfl_xor(cmx[t], 16));
        cm = fmaxf(cm, __shfl_xor(cm, 32));
        m[t] = fmaxf(cm, MFLOOR_);
      }
    } else {
      bool ok = (cmx[0] - m[0] <= DEFER_) && (cmx[1] - m[1] <= DEFER_);
      if (!__all(ok)) {          // rare: full reduce + rescale both tiles
#pragma unroll
        for (int t = 0; t < 2; ++t) {
          float cm = fmaxf(cmx[t], __shfl_xor(cmx[t], 16));
          cm = fmaxf(cm, __shfl_xor(cm, 32));
          float mn = fmaxf(fmaxf(m[t], cm), MFLOOR_);
          float al = exp2f((m[t] - mn) * L2E_);
          ls[t] *= al;
          float alr[4];
#pragma unroll
          for (int r = 0; r < 4; ++r) alr[r] = __shfl(al, g * 4 + r);
#pragma unroll
          for (int nt = 0; nt < 8; ++nt)
#pragma unroll
            for (int r = 0; r < 4; ++r) oacc[t][nt][r] *= alr[r];
          m[t] = mn;
        }
      }
    }

    // ---- p = exp, accumulate l, pack PV A-fragments (lane-local) ----
    s8 pa[2];
#pragma unroll
    for (int t = 0; t < 2; ++t) {
      float pv[8];
#pragma unroll
      for (int t2 = 0; t2 < 2; ++t2)
#pragma unroll
        for (int r = 0; r < 4; ++r) {
          float p = exp2f((st[t2][t][r] - m[t]) * L2E_);
          ls[t] += p;
          pv[t2 * 4 + r] = p;
        }
      frag_u up;
      up.w[0] = pack2(pv[0], pv[1]); up.w[1] = pack2(pv[2], pv[3]);
      up.w[2] = pack2(pv[4], pv[5]); up.w[3] = pack2(pv[6], pv[7]);
      pa[t] = up.v;
    }

    // ---- PV: V fragment read once, used by both q-tiles ----
    __builtin_amdgcn_s_setprio(1);
#pragma unroll
    for (int nt = 0; nt < 8; ++nt) {
      const short* vp = vT + (nt * 16 + l15) * 36 + g * 4;
      s4 b0 = *reinterpret_cast<const s4*>(vp);
      s4 b1 = *reinterpret_cast<const s4*>(vp + 16);
      s8 vb2 = { b0[0], b0[1], b0[2], b0[3], b1[0], b1[1], b1[2], b1[3] };
      oacc[0][nt] = __builtin_amdgcn_mfma_f32_16x16x32_bf16(pa[0], vb2, oacc[0][nt], 0, 0, 0);
      oacc[1][nt] = __builtin_amdgcn_mfma_f32_16x16x32_bf16(pa[1], vb2, oacc[1][nt], 0, 0, 0);
    }
    __builtin_amdgcn_s_setprio(0);
    // no barrier: same-wave LDS WAR/RAW ordering is in-order (r6-verified)
  }

  // ---- epilogue per q-tile: reduce l, redistribute, normalize, store ----
#pragma unroll
  for (int t = 0; t < 2; ++t) {
    float l = ls[t];
    l += __shfl_xor(l, 16);
    l += __shfl_xor(l, 32);
    float linv[4];
#pragma unroll
    for (int r = 0; r < 4; ++r) {
      float lq = __shfl(l, g * 4 + r);
      linv[r] = kp ? (1.0f / lq) : 0.0f;
    }
    float* ob = out + ((size_t)h * NQ_ + (size_t)n * BS_ + t * 16 + g * 4) * D_ + l15;
#pragma unroll
    for (int nt = 0; nt < 8; ++nt)
#pragma unroll
      for (int r = 0; r < 4; ++r)
        ob[(size_t)r * D_ + nt * 16] = oacc[t][nt][r] * linv[r];
  }
}

extern "C" void kernel_launch(void* const* d_in, const int* in_sizes, int n_in,
                              void* d_out, int out_size, void* d_ws, size_t ws_size,
                              hipStream_t stream) {
  (void)in_sizes; (void)n_in; (void)d_ws; (void)ws_size; (void)out_size;
  const float* q       = (const float*)d_in[0];
  const float* k_ctx   = (const float*)d_in[1];
  const float* v_ctx   = (const float*)d_in[2];
  const float* k_draft = (const float*)d_in[3];
  const float* v_draft = (const float*)d_in[4];
  const int*   anchor  = (const int*)d_in[5];
  const int*   keep    = (const int*)d_in[6];
  float*       out     = (float*)d_out;
  mtp_attn_kernel<<<dim3(8192), dim3(64), 0, stream>>>(
      q, k_ctx, v_ctx, k_draft, v_draft, anchor, keep, out);
}